// Round 11
// baseline (155.531 us; speedup 1.0000x reference)
//
#include <hip/hip_runtime.h>

#define C_GMS 0.0026f

// DPP wavefront shifts: full-rate VALU cross-lane, zero LDS latency.
__device__ __forceinline__ float dppL(float x) {
    return __int_as_float(__builtin_amdgcn_mov_dpp(__float_as_int(x), 0x138, 0xf, 0xf, true));
}
__device__ __forceinline__ float dppR(float x) {
    return __int_as_float(__builtin_amdgcn_mov_dpp(__float_as_int(x), 0x130, 0xf, 0xf, true));
}
__device__ __forceinline__ float med3f(float a, float b, float c) {
    return __builtin_amdgcn_fmed3f(a, b, c);
}

// partial layout: [0,2560) scale0 | [,4096) s1 | [,4352) s2 | [,4608) s3
// R10/R11: DECOUPLE. 9 rounds pinned the fused scale0 at ~2 TB/s (dependent
// stencil shape). msgms_gray = pure m13-shaped streaming RGB->gray
// (float4, grid-stride, no consumer chain) at full BW; scale0 then reads
// 2 L3-resident gray streams/row instead of 6 cold RGB streams.
#define N0 2560
#define N1 1536
#define N2 256
#define N3 256
#define NTOT 4608

// ---------- Dispatch 0: RGB -> gray, pure streaming -----------------------
__global__ __launch_bounds__(256) void msgms_gray(
    const float* __restrict__ Ii, const float* __restrict__ Ir,
    float* __restrict__ X0, float* __restrict__ Y0)
{
    const int tid = blockIdx.x * 256 + threadIdx.x;
    const int NT  = 2048 * 256;
    // 2 * 16 * 65536 float4 items (X then Y), contiguous per wave
    for (int idx = tid; idx < (2 << 20); idx += NT) {
        const int sel = idx >> 20;           // 0: X (Ii), 1: Y (Ir)
        const int o4  = idx & 0xFFFFF;
        const int img = o4 >> 16;            // 65536 float4 per image
        const int f   = o4 & 0xFFFF;
        const float* src = (sel ? Ir : Ii) + (size_t)img * 786432 + (size_t)f * 4;
        float4 a = *(const float4*)(src);
        float4 b = *(const float4*)(src + 262144);
        float4 c = *(const float4*)(src + 524288);
        float4 g;
        g.x = (a.x + b.x + c.x) * (1.0f / 3.0f);
        g.y = (a.y + b.y + c.y) * (1.0f / 3.0f);
        g.z = (a.z + b.z + c.z) * (1.0f / 3.0f);
        g.w = (a.w + b.w + c.w) * (1.0f / 3.0f);
        float* dst = (sel ? Y0 : X0) + (size_t)img * 262144 + (size_t)f * 4;
        *(float4*)dst = g;
    }
}

// ---------- scalar rolling core (scale 3 only) ----------------------------
template<int TRIP, class LoadFn, class PoolFn>
__device__ __forceinline__ float gms_core(int lane, int Hk, int R0, int iend, int c,
                                          int phalf, LoadFn loadrow2, PoolFn dopool)
{
    auto medrow = [&](float ga, float gb, float gc, float& m, float& rs) {
        float lo = fminf(fminf(ga, gb), gc);
        float me = med3f(ga, gb, gc);
        float hi = fmaxf(fmaxf(ga, gb), gc);
        float lmax = fmaxf(fmaxf(dppL(lo), lo), dppR(lo));
        float mid  = med3f(dppL(me), me, dppR(me));
        float hmin = fminf(fminf(dppL(hi), hi), dppR(hi));
        m  = med3f(lmax, mid, hmin);
        rs = m + dppL(m) + dppR(m);
    };

    float xa, ya, xb, yb, xc, yc, xd, yd, xe, ye;
    loadrow2(R0 - 1, xa, ya);
    loadrow2(R0,     xb, yb);
    loadrow2(R0 + 1, xc, yc);
    loadrow2(R0 + 2, xd, yd);
    loadrow2(R0 + 3, xe, ye);

    float n0x, n0y, n1x, n1y;
    loadrow2(R0 + 4, n0x, n0y);
    loadrow2(R0 + 5, n1x, n1y);

    float mx0, mx1, mx2, rx0, rx1, rx2;
    float my0, my1, my2, ry0, ry1, ry2;
    medrow(xa, xb, xc, mx0, rx0); medrow(ya, yb, yc, my0, ry0);
    dopool(xb, xc, yb, yc, phalf);
    medrow(xb, xc, xd, mx1, rx1); medrow(yb, yc, yd, my1, ry1);
    medrow(xc, xd, xe, mx2, rx2); medrow(yc, yd, ye, my2, ry2);

    float gx2 = xd, gx3 = xe, gy2 = yd, gy3 = ye;
    const bool outLane = (lane >= 2) && (lane <= 61) && (c <= Hk - 2);
    const float C9 = 9.0f * C_GMS;
    float acc = 0.0f;

    #pragma unroll
    for (int j = 0; j < TRIP; ++j) {
        const int i = R0 + j;
        float pfx, pfy;
        {
            int rp = (i + 6 <= iend + 3) ? (i + 6) : -1;
            loadrow2(rp, pfx, pfy);
        }

        float csx = mx0 + mx1 + mx2;
        float csy = my0 + my1 + my2;
        float Gxx = dppR(csx) - dppL(csx);
        float Gxy = dppR(csy) - dppL(csy);
        float Gyx = rx0 - rx2;
        float Gyy = ry0 - ry2;
        float a = fmaf(Gxx, Gxx, Gyx * Gyx);
        float b = fmaf(Gxy, Gxy, Gyy * Gyy);
        float t = a + b;
        float s = __builtin_amdgcn_sqrtf(a * b);
        float diff = fmaf(-2.0f, s, t);
        float r = __builtin_amdgcn_rcpf(t + C9);
        if (outLane && (i < iend)) acc = fmaf(diff, r, acc);

        if (((i + 3) & 1) == 1) dopool(gx2, gx3, gy2, gy3, (i + 2) >> 1);

        float mxn, rxn, myn, ryn;
        medrow(gx2, gx3, n0x, mxn, rxn);
        medrow(gy2, gy3, n0y, myn, ryn);
        mx0 = mx1; mx1 = mx2; mx2 = mxn; rx0 = rx1; rx1 = rx2; rx2 = rxn;
        my0 = my1; my1 = my2; my2 = myn; ry0 = ry1; ry1 = ry2; ry2 = ryn;
        gx2 = gx3; gx3 = n0x; gy2 = gy3; gy3 = n0y;
        n0x = n1x; n0y = n1y; n1x = pfx; n1y = pfy;
    }

    for (int off = 32; off; off >>= 1) acc += __shfl_down(acc, off, 64);
    return acc;
}

// ---------- float2 rolling core (2 adjacent cols/lane) --------------------
// Proven exact on scale0 in R7/R9 (absmax 0.0).
template<int TRIP, class LoadFn, class PoolFn>
__device__ __forceinline__ float gms_core2(int R0, int iend, bool out0, bool out1,
                                           int phalf, LoadFn loadrow2, PoolFn dopool)
{
    auto medrow = [&](float2 ga, float2 gb, float2 gc, float2& m, float2& rs) {
        float lo0 = fminf(fminf(ga.x, gb.x), gc.x);
        float lo1 = fminf(fminf(ga.y, gb.y), gc.y);
        float me0 = med3f(ga.x, gb.x, gc.x);
        float me1 = med3f(ga.y, gb.y, gc.y);
        float hi0 = fmaxf(fmaxf(ga.x, gb.x), gc.x);
        float hi1 = fmaxf(fmaxf(ga.y, gb.y), gc.y);
        float lmax0 = fmaxf(fmaxf(dppL(lo1), lo0), lo1);
        float lmax1 = fmaxf(fmaxf(lo0, lo1), dppR(lo0));
        float mid0  = med3f(dppL(me1), me0, me1);
        float mid1  = med3f(me0, me1, dppR(me0));
        float hmin0 = fminf(fminf(dppL(hi1), hi0), hi1);
        float hmin1 = fminf(fminf(hi0, hi1), dppR(hi0));
        m.x = med3f(lmax0, mid0, hmin0);
        m.y = med3f(lmax1, mid1, hmin1);
        float ms = m.x + m.y;
        rs.x = dppL(m.y) + ms;
        rs.y = ms + dppR(m.x);
    };

    float2 xa, ya, xb, yb, xc, yc, xd, yd, xe, ye;
    loadrow2(R0 - 1, xa, ya);
    loadrow2(R0,     xb, yb);
    loadrow2(R0 + 1, xc, yc);
    loadrow2(R0 + 2, xd, yd);
    loadrow2(R0 + 3, xe, ye);

    float2 n0x, n0y, n1x, n1y;
    loadrow2(R0 + 4, n0x, n0y);
    loadrow2(R0 + 5, n1x, n1y);

    float2 mx0, mx1, mx2, rx0, rx1, rx2;
    float2 my0, my1, my2, ry0, ry1, ry2;
    medrow(xa, xb, xc, mx0, rx0); medrow(ya, yb, yc, my0, ry0);
    dopool(xb, xc, yb, yc, phalf);
    medrow(xb, xc, xd, mx1, rx1); medrow(yb, yc, yd, my1, ry1);
    medrow(xc, xd, xe, mx2, rx2); medrow(yc, yd, ye, my2, ry2);

    float2 gx2 = xd, gx3 = xe, gy2 = yd, gy3 = ye;
    const float C9 = 9.0f * C_GMS;
    float acc = 0.0f;

    #pragma unroll
    for (int j = 0; j < TRIP; ++j) {
        const int i = R0 + j;
        float2 pfx, pfy;
        {
            int rp = (i + 6 <= iend + 3) ? (i + 6) : -1;
            loadrow2(rp, pfx, pfy);
        }

        float2 csx, csy;
        csx.x = mx0.x + mx1.x + mx2.x; csx.y = mx0.y + mx1.y + mx2.y;
        csy.x = my0.x + my1.x + my2.x; csy.y = my0.y + my1.y + my2.y;
        float Gxx0 = csx.y - dppL(csx.y), Gxx1 = dppR(csx.x) - csx.x;
        float Gxy0 = csy.y - dppL(csy.y), Gxy1 = dppR(csy.x) - csy.x;
        float Gyx0 = rx0.x - rx2.x,       Gyx1 = rx0.y - rx2.y;
        float Gyy0 = ry0.x - ry2.x,       Gyy1 = ry0.y - ry2.y;

        float a0 = fmaf(Gxx0, Gxx0, Gyx0 * Gyx0);
        float b0 = fmaf(Gxy0, Gxy0, Gyy0 * Gyy0);
        float t0 = a0 + b0;
        float s0 = __builtin_amdgcn_sqrtf(a0 * b0);
        float d0 = fmaf(-2.0f, s0, t0);
        float r0 = __builtin_amdgcn_rcpf(t0 + C9);
        if (out0 && (i < iend)) acc = fmaf(d0, r0, acc);

        float a1 = fmaf(Gxx1, Gxx1, Gyx1 * Gyx1);
        float b1 = fmaf(Gxy1, Gxy1, Gyy1 * Gyy1);
        float t1v = a1 + b1;
        float s1 = __builtin_amdgcn_sqrtf(a1 * b1);
        float d1 = fmaf(-2.0f, s1, t1v);
        float r1 = __builtin_amdgcn_rcpf(t1v + C9);
        if (out1 && (i < iend)) acc = fmaf(d1, r1, acc);

        if (((i + 3) & 1) == 1) dopool(gx2, gx3, gy2, gy3, (i + 2) >> 1);

        float2 mxn, rxn, myn, ryn;
        medrow(gx2, gx3, n0x, mxn, rxn);
        medrow(gy2, gy3, n0y, myn, ryn);
        mx0 = mx1; mx1 = mx2; mx2 = mxn; rx0 = rx1; rx1 = rx2; rx2 = rxn;
        my0 = my1; my1 = my2; my2 = myn; ry0 = ry1; ry1 = ry2; ry2 = ryn;
        gx2 = gx3; gx3 = n0x; gy2 = gy3; gy3 = n0y;
        n0x = n1x; n0y = n1y; n1x = pfx; n1y = pfy;
    }

    for (int off = 32; off; off >>= 1) acc += __shfl_down(acc, off, 64);
    return acc;
}

// ---------- Dispatch A: scale0 from PRE-COMPUTED gray (2 loads/row) -------
__global__ __launch_bounds__(256) void msgms_scale0(
    const float* __restrict__ X0, const float* __restrict__ Y0,
    float* __restrict__ X1, float* __restrict__ Y1, float* __restrict__ P)
{
    const int lane = threadIdx.x & 63;
    const int u = blockIdx.x * 4 + (threadIdx.x >> 6);   // 0..2559
    const int s  = u % 5;
    const int t1 = u / 5;
    const int k  = t1 % 32;             // 32 chunks of 16 rows
    const int b  = t1 / 32;

    const int B  = 120 * s;             // strip base col (even)
    const int c0 = B + 2 * lane;
    const int R0 = k * 16;
    const int iend = min(R0 + 16, 510);

    const float* GX = X0 + (size_t)b * 262144;
    const float* GY = Y0 + (size_t)b * 262144;

    const int cc = min(c0, 510);
    const float cw = (c0 <= 511) ? 1.0f : 0.0f;

    auto loadrow2 = [&](int r, float2& vx, float2& vy) {
        int rc = min(max(r, 0), 511);          // uniform (SALU)
        float m = (r == rc) ? cw : 0.0f;
        int o = rc * 512 + cc;                 // even -> 8B aligned
        float2 gx = *(const float2*)(GX + o);
        float2 gy = *(const float2*)(GY + o);
        vx.x = gx.x * m; vx.y = gx.y * m;
        vy.x = gy.x * m; vy.y = gy.y * m;
    };

    // exclusive output-ownership per strip (covers 1..510 exactly once)
    const int ostart = (s == 0) ? 1 : (120 * s + 6);
    const int oend   = (s == 4) ? 510 : (120 * s + 125);
    const bool out0 = (c0 >= ostart)     && (c0 <= oend);
    const bool out1 = (c0 + 1 >= ostart) && (c0 + 1 <= oend);

    // pool: lane-local pair -> pooled col q = c0/2; exclusive ownership
    const int q = 60 * s + lane;
    const bool poolLane = (lane < ((s == 4) ? 16 : 60));
    const int phalf = R0 >> 1;
    const int pend  = min(phalf + 8, 256);
    auto dopool = [&](float2 bx, float2 cx, float2 by, float2 cy, int p) {
        if (p < phalf || p >= pend) return;   // uniform
        if (poolLane) {
            size_t o = ((size_t)b * 256 + p) * 256 + q;
            X1[o] = ((bx.x + bx.y) + (cx.x + cx.y)) * 0.25f;
            Y1[o] = ((by.x + by.y) + (cy.x + cy.y)) * 0.25f;
        }
    };

    float acc = gms_core2<16>(R0, iend, out0, out1, phalf, loadrow2, dopool);
    if (lane == 0) P[u] = acc;
}

// ---------- Dispatch B: scales 1-3 (unchanged from R9) --------------------
__device__ __forceinline__ void phaseR1f2(
    int v, const float* __restrict__ X1, const float* __restrict__ Y1,
    float* __restrict__ P)
{
    const int lane = threadIdx.x & 63;
    const int s  = v % 3;
    const int t1 = v / 3;
    const int k  = t1 % 32;
    const int b  = t1 / 32;

    const int c0 = 96 * s + 2 * lane;
    const int R0 = k * 8;
    const int iend = min(R0 + 8, 254);

    const float* Xp = X1 + (size_t)b * 65536;
    const float* Yp = Y1 + (size_t)b * 65536;

    const int cc = min(c0, 254);
    const float cw = (c0 <= 254) ? 1.0f : 0.0f;

    auto loadrow2 = [&](int r, float2& vx, float2& vy) {
        int rc = min(max(r, 0), 255);
        float m = (r == rc) ? cw : 0.0f;
        int o = rc * 256 + cc;
        float2 ax = *(const float2*)(Xp + o);
        float2 ay = *(const float2*)(Yp + o);
        vx.x = ax.x * m; vx.y = ax.y * m;
        vy.x = ay.x * m; vy.y = ay.y * m;
    };
    auto nopool = [&](float2, float2, float2, float2, int) {};

    const int ostart = (s == 0) ? 1   : (96 * s + 8);
    const int oend   = (s == 2) ? 254 : (96 * s + 103);
    const bool out0 = (c0 >= ostart)     && (c0 <= oend);
    const bool out1 = (c0 + 1 >= ostart) && (c0 + 1 <= oend);

    float acc = gms_core2<8>(R0, iend, out0, out1, 0, loadrow2, nopool);
    if (lane == 0) P[v] = acc;
}

__device__ __forceinline__ void phaseR2f2(
    int v, const float* __restrict__ X1, const float* __restrict__ Y1,
    float* __restrict__ P)
{
    const int lane = threadIdx.x & 63;
    const int k  = v % 16;
    const int b  = v / 16;

    const int c0 = 2 * lane;
    const int R0 = k * 8;
    const int iend = min(R0 + 8, 126);

    const float* Xp = X1 + (size_t)b * 65536;
    const float* Yp = Y1 + (size_t)b * 65536;

    auto loadrow2 = [&](int r, float2& vx, float2& vy) {
        int rc = min(max(r, 0), 127);
        float m = (r == rc) ? 0.25f : 0.0f;
        int o = (rc * 2) * 256 + 4 * lane;
        float4 a0 = *(const float4*)(Xp + o);
        float4 a1 = *(const float4*)(Xp + o + 256);
        float4 b0 = *(const float4*)(Yp + o);
        float4 b1 = *(const float4*)(Yp + o + 256);
        vx.x = ((a0.x + a0.y) + (a1.x + a1.y)) * m;
        vx.y = ((a0.z + a0.w) + (a1.z + a1.w)) * m;
        vy.x = ((b0.x + b0.y) + (b1.x + b1.y)) * m;
        vy.y = ((b0.z + b0.w) + (b1.z + b1.w)) * m;
    };
    auto nopool = [&](float2, float2, float2, float2, int) {};

    const bool out0 = (c0 >= 1) && (c0 <= 126);
    const bool out1 = (c0 + 1 >= 1) && (c0 + 1 <= 126);

    float acc = gms_core2<8>(R0, iend, out0, out1, 0, loadrow2, nopool);
    if (lane == 0) P[v] = acc;
}

__device__ __forceinline__ void phaseR4(
    int u, const float* __restrict__ X1, const float* __restrict__ Y1,
    float* __restrict__ P)
{
    constexpr int Hk = 64;
    const int lane = threadIdx.x & 63;
    const int s  = u % 2;
    const int t1 = u / 2;
    const int k  = t1 % 8;
    const int b  = t1 / 8;

    const int c  = 60 * s - 1 + lane;
    const int R0 = k * 8;
    const int iend = min(R0 + 8, Hk - 2);

    const float* Xp = X1 + (size_t)b * 65536;
    const float* Yp = Y1 + (size_t)b * 65536;

    const int cc = min(max(c, 0), Hk - 1);
    const float cval = ((c >= 0) && (c < Hk)) ? 1.0f : 0.0f;

    auto loadrow2 = [&](int r, float& vx, float& vy) {
        int rc = min(max(r, 0), Hk - 1);
        float m = (r == rc) ? cval : 0.0f;
        int o = (rc * 4) * 256 + cc * 4;
        float sx = 0.0f, sy = 0.0f;
        #pragma unroll
        for (int fr = 0; fr < 4; ++fr) {
            float4 t = *(const float4*)(Xp + o + fr * 256);
            float4 qv = *(const float4*)(Yp + o + fr * 256);
            sx += (t.x + t.y) + (t.z + t.w);
            sy += (qv.x + qv.y) + (qv.z + qv.w);
        }
        float qq = 0.0625f * m;
        vx = sx * qq; vy = sy * qq;
    };
    auto nopool = [&](float, float, float, float, int) {};

    float acc = gms_core<8>(lane, Hk, R0, iend, c, 0, loadrow2, nopool);
    if (lane == 0) P[u] = acc;
}

__global__ __launch_bounds__(256) void msgms_rest(
    const float* __restrict__ X1, const float* __restrict__ Y1,
    float* __restrict__ P)
{
    const int u = blockIdx.x * 4 + (threadIdx.x >> 6);
    if      (u < N1)      phaseR1f2(u,           X1, Y1, P + N0);
    else if (u < N1 + N2) phaseR2f2(u - N1,      X1, Y1, P + N0 + N1);
    else                  phaseR4 (u - N1 - N2,  X1, Y1, P + N0 + N1 + N2);
}

// Dispatch C: one block, weighted sum of all partials.
__global__ __launch_bounds__(256) void msgms_final(
    const float* __restrict__ P, float* __restrict__ out)
{
    const int tid = threadIdx.x;
    const double w0 = 1.0 / (4.0 * 16.0 * 510.0 * 510.0);
    const double w1 = 1.0 / (4.0 * 16.0 * 254.0 * 254.0);
    const double w2 = 1.0 / (4.0 * 16.0 * 126.0 * 126.0);
    const double w3 = 1.0 / (4.0 * 16.0 * 62.0 * 62.0);
    double v = 0.0;
    for (int i = tid; i < NTOT; i += 256) {
        double w = (i < N0) ? w0 : (i < N0 + N1) ? w1 : (i < N0 + N1 + N2) ? w2 : w3;
        v += (double)P[i] * w;
    }
    for (int off = 32; off; off >>= 1) v += __shfl_down(v, off, 64);
    __shared__ double wsum[4];
    if ((tid & 63) == 0) wsum[tid >> 6] = v;
    __syncthreads();
    if (tid == 0) out[0] = (float)(wsum[0] + wsum[1] + wsum[2] + wsum[3]);
}

extern "C" void kernel_launch(void* const* d_in, const int* in_sizes, int n_in,
                              void* d_out, int out_size, void* d_ws, size_t ws_size,
                              hipStream_t stream) {
    const float* Ii = (const float*)d_in[0];
    const float* Ir = (const float*)d_in[1];
    float* out = (float*)d_out;

    char* ws = (char*)d_ws;
    float* P  = (float*)ws;                              // NTOT partials
    float* X1 = P + NTOT;                                // 16 x 256 x 256 gray s1
    float* Y1 = X1 + 16 * 65536;
    float* X0 = Y1 + 16 * 65536;                         // 16 x 512 x 512 gray s0
    float* Y0 = X0 + 16 * 262144;

    msgms_gray  <<<2048, 256, 0, stream>>>(Ii, Ir, X0, Y0);
    msgms_scale0<<<N0 / 4, 256, 0, stream>>>(X0, Y0, X1, Y1, P);
    msgms_rest  <<<(N1 + N2 + N3) / 4, 256, 0, stream>>>(X1, Y1, P);
    msgms_final <<<1, 256, 0, stream>>>(P, out);
}

// Round 12
// 139.405 us; speedup vs baseline: 1.1157x; 1.1157x over previous
//
#include <hip/hip_runtime.h>

#define C_GMS 0.0026f

// DPP wavefront shifts: full-rate VALU cross-lane, zero LDS latency.
// dppL = value of lane-1 (wf_shr:1, 0x138), lane 0 reads 0 (bound_ctrl)
// dppR = value of lane+1 (wf_shl:1, 0x130), lane 63 reads 0
__device__ __forceinline__ float dppL(float x) {
    return __int_as_float(__builtin_amdgcn_mov_dpp(__float_as_int(x), 0x138, 0xf, 0xf, true));
}
__device__ __forceinline__ float dppR(float x) {
    return __int_as_float(__builtin_amdgcn_mov_dpp(__float_as_int(x), 0x130, 0xf, 0xf, true));
}
__device__ __forceinline__ float med3f(float a, float b, float c) {
    return __builtin_amdgcn_fmed3f(a, b, c);
}

// partial layout: [0,2560) scale0 | [,4096) s1 | [,4352) s2 | [,4608) s3
// R12 = R9 verbatim (best measured: 140.2 us, absmax 0.0).
// Session ledger: fills ~82us (harness) + scale0 ~41 (7 variants pinned at
// ~2 TB/s on the fused 6-stream stencil; decoupled gray pre-pass measured
// NET SLOWER, R11) + rest ~15 + final ~2. Hard floor ~131; this is ~7% above,
// all of it the stencil-shape BW gap that R1-R11 could not move.
#define N0 2560
#define N1 1536
#define N2 256
#define N3 256
#define NTOT 4608

// ---------- scalar rolling core (scale 3 only) ----------------------------
template<int TRIP, class LoadFn, class PoolFn>
__device__ __forceinline__ float gms_core(int lane, int Hk, int R0, int iend, int c,
                                          int phalf, LoadFn loadrow2, PoolFn dopool)
{
    auto medrow = [&](float ga, float gb, float gc, float& m, float& rs) {
        float lo = fminf(fminf(ga, gb), gc);
        float me = med3f(ga, gb, gc);
        float hi = fmaxf(fmaxf(ga, gb), gc);
        float lmax = fmaxf(fmaxf(dppL(lo), lo), dppR(lo));
        float mid  = med3f(dppL(me), me, dppR(me));
        float hmin = fminf(fminf(dppL(hi), hi), dppR(hi));
        m  = med3f(lmax, mid, hmin);
        rs = m + dppL(m) + dppR(m);
    };

    float xa, ya, xb, yb, xc, yc, xd, yd, xe, ye;
    loadrow2(R0 - 1, xa, ya);
    loadrow2(R0,     xb, yb);
    loadrow2(R0 + 1, xc, yc);
    loadrow2(R0 + 2, xd, yd);
    loadrow2(R0 + 3, xe, ye);

    float n0x, n0y, n1x, n1y;
    loadrow2(R0 + 4, n0x, n0y);
    loadrow2(R0 + 5, n1x, n1y);

    float mx0, mx1, mx2, rx0, rx1, rx2;
    float my0, my1, my2, ry0, ry1, ry2;
    medrow(xa, xb, xc, mx0, rx0); medrow(ya, yb, yc, my0, ry0);
    dopool(xb, xc, yb, yc, phalf);
    medrow(xb, xc, xd, mx1, rx1); medrow(yb, yc, yd, my1, ry1);
    medrow(xc, xd, xe, mx2, rx2); medrow(yc, yd, ye, my2, ry2);

    float gx2 = xd, gx3 = xe, gy2 = yd, gy3 = ye;
    const bool outLane = (lane >= 2) && (lane <= 61) && (c <= Hk - 2);
    const float C9 = 9.0f * C_GMS;
    float acc = 0.0f;

    #pragma unroll
    for (int j = 0; j < TRIP; ++j) {
        const int i = R0 + j;
        float pfx, pfy;
        {
            int rp = (i + 6 <= iend + 3) ? (i + 6) : -1;
            loadrow2(rp, pfx, pfy);
        }

        float csx = mx0 + mx1 + mx2;
        float csy = my0 + my1 + my2;
        float Gxx = dppR(csx) - dppL(csx);
        float Gxy = dppR(csy) - dppL(csy);
        float Gyx = rx0 - rx2;
        float Gyy = ry0 - ry2;
        float a = fmaf(Gxx, Gxx, Gyx * Gyx);
        float b = fmaf(Gxy, Gxy, Gyy * Gyy);
        float t = a + b;
        float s = __builtin_amdgcn_sqrtf(a * b);
        float diff = fmaf(-2.0f, s, t);
        float r = __builtin_amdgcn_rcpf(t + C9);
        if (outLane && (i < iend)) acc = fmaf(diff, r, acc);

        if (((i + 3) & 1) == 1) dopool(gx2, gx3, gy2, gy3, (i + 2) >> 1);

        float mxn, rxn, myn, ryn;
        medrow(gx2, gx3, n0x, mxn, rxn);
        medrow(gy2, gy3, n0y, myn, ryn);
        mx0 = mx1; mx1 = mx2; mx2 = mxn; rx0 = rx1; rx1 = rx2; rx2 = rxn;
        my0 = my1; my1 = my2; my2 = myn; ry0 = ry1; ry1 = ry2; ry2 = ryn;
        gx2 = gx3; gx3 = n0x; gy2 = gy3; gy3 = n0y;
        n0x = n1x; n0y = n1y; n1x = pfx; n1y = pfy;
    }

    for (int off = 32; off; off >>= 1) acc += __shfl_down(acc, off, 64);
    return acc;
}

// ---------- float2 rolling core (2 adjacent cols/lane) --------------------
// Proven exact on scale0 in R7/R9 (absmax 0.0).
template<int TRIP, class LoadFn, class PoolFn>
__device__ __forceinline__ float gms_core2(int R0, int iend, bool out0, bool out1,
                                           int phalf, LoadFn loadrow2, PoolFn dopool)
{
    auto medrow = [&](float2 ga, float2 gb, float2 gc, float2& m, float2& rs) {
        float lo0 = fminf(fminf(ga.x, gb.x), gc.x);
        float lo1 = fminf(fminf(ga.y, gb.y), gc.y);
        float me0 = med3f(ga.x, gb.x, gc.x);
        float me1 = med3f(ga.y, gb.y, gc.y);
        float hi0 = fmaxf(fmaxf(ga.x, gb.x), gc.x);
        float hi1 = fmaxf(fmaxf(ga.y, gb.y), gc.y);
        float lmax0 = fmaxf(fmaxf(dppL(lo1), lo0), lo1);
        float lmax1 = fmaxf(fmaxf(lo0, lo1), dppR(lo0));
        float mid0  = med3f(dppL(me1), me0, me1);
        float mid1  = med3f(me0, me1, dppR(me0));
        float hmin0 = fminf(fminf(dppL(hi1), hi0), hi1);
        float hmin1 = fminf(fminf(hi0, hi1), dppR(hi0));
        m.x = med3f(lmax0, mid0, hmin0);
        m.y = med3f(lmax1, mid1, hmin1);
        float ms = m.x + m.y;
        rs.x = dppL(m.y) + ms;
        rs.y = ms + dppR(m.x);
    };

    float2 xa, ya, xb, yb, xc, yc, xd, yd, xe, ye;
    loadrow2(R0 - 1, xa, ya);
    loadrow2(R0,     xb, yb);
    loadrow2(R0 + 1, xc, yc);
    loadrow2(R0 + 2, xd, yd);
    loadrow2(R0 + 3, xe, ye);

    float2 n0x, n0y, n1x, n1y;
    loadrow2(R0 + 4, n0x, n0y);
    loadrow2(R0 + 5, n1x, n1y);

    float2 mx0, mx1, mx2, rx0, rx1, rx2;
    float2 my0, my1, my2, ry0, ry1, ry2;
    medrow(xa, xb, xc, mx0, rx0); medrow(ya, yb, yc, my0, ry0);
    dopool(xb, xc, yb, yc, phalf);
    medrow(xb, xc, xd, mx1, rx1); medrow(yb, yc, yd, my1, ry1);
    medrow(xc, xd, xe, mx2, rx2); medrow(yc, yd, ye, my2, ry2);

    float2 gx2 = xd, gx3 = xe, gy2 = yd, gy3 = ye;
    const float C9 = 9.0f * C_GMS;
    float acc = 0.0f;

    #pragma unroll
    for (int j = 0; j < TRIP; ++j) {
        const int i = R0 + j;
        float2 pfx, pfy;
        {
            int rp = (i + 6 <= iend + 3) ? (i + 6) : -1;
            loadrow2(rp, pfx, pfy);
        }

        float2 csx, csy;
        csx.x = mx0.x + mx1.x + mx2.x; csx.y = mx0.y + mx1.y + mx2.y;
        csy.x = my0.x + my1.x + my2.x; csy.y = my0.y + my1.y + my2.y;
        float Gxx0 = csx.y - dppL(csx.y), Gxx1 = dppR(csx.x) - csx.x;
        float Gxy0 = csy.y - dppL(csy.y), Gxy1 = dppR(csy.x) - csy.x;
        float Gyx0 = rx0.x - rx2.x,       Gyx1 = rx0.y - rx2.y;
        float Gyy0 = ry0.x - ry2.x,       Gyy1 = ry0.y - ry2.y;

        float a0 = fmaf(Gxx0, Gxx0, Gyx0 * Gyx0);
        float b0 = fmaf(Gxy0, Gxy0, Gyy0 * Gyy0);
        float t0 = a0 + b0;
        float s0 = __builtin_amdgcn_sqrtf(a0 * b0);
        float d0 = fmaf(-2.0f, s0, t0);
        float r0 = __builtin_amdgcn_rcpf(t0 + C9);
        if (out0 && (i < iend)) acc = fmaf(d0, r0, acc);

        float a1 = fmaf(Gxx1, Gxx1, Gyx1 * Gyx1);
        float b1 = fmaf(Gxy1, Gxy1, Gyy1 * Gyy1);
        float t1v = a1 + b1;
        float s1 = __builtin_amdgcn_sqrtf(a1 * b1);
        float d1 = fmaf(-2.0f, s1, t1v);
        float r1 = __builtin_amdgcn_rcpf(t1v + C9);
        if (out1 && (i < iend)) acc = fmaf(d1, r1, acc);

        if (((i + 3) & 1) == 1) dopool(gx2, gx3, gy2, gy3, (i + 2) >> 1);

        float2 mxn, rxn, myn, ryn;
        medrow(gx2, gx3, n0x, mxn, rxn);
        medrow(gy2, gy3, n0y, myn, ryn);
        mx0 = mx1; mx1 = mx2; mx2 = mxn; rx0 = rx1; rx1 = rx2; rx2 = rxn;
        my0 = my1; my1 = my2; my2 = myn; ry0 = ry1; ry1 = ry2; ry2 = ryn;
        gx2 = gx3; gx3 = n0x; gy2 = gy3; gy3 = n0y;
        n0x = n1x; n0y = n1y; n1x = pfx; n1y = pfy;
    }

    for (int off = 32; off; off >>= 1) acc += __shfl_down(acc, off, 64);
    return acc;
}

// ---------- Dispatch A: scale0 (fused RGB, float2, frozen) ----------------
__global__ __launch_bounds__(256) void msgms_scale0(
    const float* __restrict__ Ii, const float* __restrict__ Ir,
    float* __restrict__ X1, float* __restrict__ Y1, float* __restrict__ P)
{
    const int lane = threadIdx.x & 63;
    const int u = blockIdx.x * 4 + (threadIdx.x >> 6);   // 0..2559
    const int s  = u % 5;
    const int t1 = u / 5;
    const int k  = t1 % 32;             // 32 chunks of 16 rows
    const int b  = t1 / 32;

    const int B  = 120 * s;             // strip base col (even)
    const int c0 = B + 2 * lane;
    const int R0 = k * 16;
    const int iend = min(R0 + 16, 510);

    const float* PX = Ii + (size_t)b * 3 * 262144;
    const float* PY = Ir + (size_t)b * 3 * 262144;

    const int cc = min(c0, 510);
    const float cw = (c0 <= 511) ? (1.0f / 3.0f) : 0.0f;

    auto loadrow2 = [&](int r, float2& vx, float2& vy) {
        int rc = min(max(r, 0), 511);          // uniform (SALU)
        float m = (r == rc) ? cw : 0.0f;
        int o = rc * 512 + cc;                 // even -> 8B aligned
        float2 x0 = *(const float2*)(PX + o);
        float2 x1 = *(const float2*)(PX + o + 262144);
        float2 x2 = *(const float2*)(PX + o + 524288);
        float2 y0 = *(const float2*)(PY + o);
        float2 y1 = *(const float2*)(PY + o + 262144);
        float2 y2 = *(const float2*)(PY + o + 524288);
        vx.x = (x0.x + x1.x + x2.x) * m; vx.y = (x0.y + x1.y + x2.y) * m;
        vy.x = (y0.x + y1.x + y2.x) * m; vy.y = (y0.y + y1.y + y2.y) * m;
    };

    // exclusive output-ownership per strip (covers 1..510 exactly once)
    const int ostart = (s == 0) ? 1 : (120 * s + 6);
    const int oend   = (s == 4) ? 510 : (120 * s + 125);
    const bool out0 = (c0 >= ostart)     && (c0 <= oend);
    const bool out1 = (c0 + 1 >= ostart) && (c0 + 1 <= oend);

    // pool: lane-local pair -> pooled col q = c0/2; exclusive ownership
    const int q = 60 * s + lane;
    const bool poolLane = (lane < ((s == 4) ? 16 : 60));
    const int phalf = R0 >> 1;
    const int pend  = min(phalf + 8, 256);
    auto dopool = [&](float2 bx, float2 cx, float2 by, float2 cy, int p) {
        if (p < phalf || p >= pend) return;   // uniform
        if (poolLane) {
            size_t o = ((size_t)b * 256 + p) * 256 + q;
            X1[o] = ((bx.x + bx.y) + (cx.x + cx.y)) * 0.25f;
            Y1[o] = ((by.x + by.y) + (cy.x + cy.y)) * 0.25f;
        }
    };

    float acc = gms_core2<16>(R0, iend, out0, out1, phalf, loadrow2, dopool);
    if (lane == 0) P[u] = acc;
}

// ---------- Dispatch B: scales 1-3 ----------------------------------------
__device__ __forceinline__ void phaseR1f2(
    int v, const float* __restrict__ X1, const float* __restrict__ Y1,
    float* __restrict__ P)
{
    const int lane = threadIdx.x & 63;
    const int s  = v % 3;
    const int t1 = v / 3;
    const int k  = t1 % 32;
    const int b  = t1 / 32;

    const int c0 = 96 * s + 2 * lane;
    const int R0 = k * 8;
    const int iend = min(R0 + 8, 254);

    const float* Xp = X1 + (size_t)b * 65536;
    const float* Yp = Y1 + (size_t)b * 65536;

    const int cc = min(c0, 254);
    const float cw = (c0 <= 254) ? 1.0f : 0.0f;

    auto loadrow2 = [&](int r, float2& vx, float2& vy) {
        int rc = min(max(r, 0), 255);
        float m = (r == rc) ? cw : 0.0f;
        int o = rc * 256 + cc;
        float2 ax = *(const float2*)(Xp + o);
        float2 ay = *(const float2*)(Yp + o);
        vx.x = ax.x * m; vx.y = ax.y * m;
        vy.x = ay.x * m; vy.y = ay.y * m;
    };
    auto nopool = [&](float2, float2, float2, float2, int) {};

    const int ostart = (s == 0) ? 1   : (96 * s + 8);
    const int oend   = (s == 2) ? 254 : (96 * s + 103);
    const bool out0 = (c0 >= ostart)     && (c0 <= oend);
    const bool out1 = (c0 + 1 >= ostart) && (c0 + 1 <= oend);

    float acc = gms_core2<8>(R0, iend, out0, out1, 0, loadrow2, nopool);
    if (lane == 0) P[v] = acc;
}

__device__ __forceinline__ void phaseR2f2(
    int v, const float* __restrict__ X1, const float* __restrict__ Y1,
    float* __restrict__ P)
{
    const int lane = threadIdx.x & 63;
    const int k  = v % 16;
    const int b  = v / 16;

    const int c0 = 2 * lane;
    const int R0 = k * 8;
    const int iend = min(R0 + 8, 126);

    const float* Xp = X1 + (size_t)b * 65536;
    const float* Yp = Y1 + (size_t)b * 65536;

    auto loadrow2 = [&](int r, float2& vx, float2& vy) {
        int rc = min(max(r, 0), 127);
        float m = (r == rc) ? 0.25f : 0.0f;
        int o = (rc * 2) * 256 + 4 * lane;
        float4 a0 = *(const float4*)(Xp + o);
        float4 a1 = *(const float4*)(Xp + o + 256);
        float4 b0 = *(const float4*)(Yp + o);
        float4 b1 = *(const float4*)(Yp + o + 256);
        vx.x = ((a0.x + a0.y) + (a1.x + a1.y)) * m;
        vx.y = ((a0.z + a0.w) + (a1.z + a1.w)) * m;
        vy.x = ((b0.x + b0.y) + (b1.x + b1.y)) * m;
        vy.y = ((b0.z + b0.w) + (b1.z + b1.w)) * m;
    };
    auto nopool = [&](float2, float2, float2, float2, int) {};

    const bool out0 = (c0 >= 1) && (c0 <= 126);
    const bool out1 = (c0 + 1 >= 1) && (c0 + 1 <= 126);

    float acc = gms_core2<8>(R0, iend, out0, out1, 0, loadrow2, nopool);
    if (lane == 0) P[v] = acc;
}

__device__ __forceinline__ void phaseR4(
    int u, const float* __restrict__ X1, const float* __restrict__ Y1,
    float* __restrict__ P)
{
    constexpr int Hk = 64;
    const int lane = threadIdx.x & 63;
    const int s  = u % 2;
    const int t1 = u / 2;
    const int k  = t1 % 8;
    const int b  = t1 / 8;

    const int c  = 60 * s - 1 + lane;
    const int R0 = k * 8;
    const int iend = min(R0 + 8, Hk - 2);

    const float* Xp = X1 + (size_t)b * 65536;
    const float* Yp = Y1 + (size_t)b * 65536;

    const int cc = min(max(c, 0), Hk - 1);
    const float cval = ((c >= 0) && (c < Hk)) ? 1.0f : 0.0f;

    auto loadrow2 = [&](int r, float& vx, float& vy) {
        int rc = min(max(r, 0), Hk - 1);
        float m = (r == rc) ? cval : 0.0f;
        int o = (rc * 4) * 256 + cc * 4;
        float sx = 0.0f, sy = 0.0f;
        #pragma unroll
        for (int fr = 0; fr < 4; ++fr) {
            float4 t = *(const float4*)(Xp + o + fr * 256);
            float4 qv = *(const float4*)(Yp + o + fr * 256);
            sx += (t.x + t.y) + (t.z + t.w);
            sy += (qv.x + qv.y) + (qv.z + qv.w);
        }
        float qq = 0.0625f * m;
        vx = sx * qq; vy = sy * qq;
    };
    auto nopool = [&](float, float, float, float, int) {};

    float acc = gms_core<8>(lane, Hk, R0, iend, c, 0, loadrow2, nopool);
    if (lane == 0) P[u] = acc;
}

__global__ __launch_bounds__(256) void msgms_rest(
    const float* __restrict__ X1, const float* __restrict__ Y1,
    float* __restrict__ P)
{
    const int u = blockIdx.x * 4 + (threadIdx.x >> 6);
    if      (u < N1)      phaseR1f2(u,           X1, Y1, P + N0);
    else if (u < N1 + N2) phaseR2f2(u - N1,      X1, Y1, P + N0 + N1);
    else                  phaseR4 (u - N1 - N2,  X1, Y1, P + N0 + N1 + N2);
}

// Dispatch C: one block, weighted sum of all partials.
__global__ __launch_bounds__(256) void msgms_final(
    const float* __restrict__ P, float* __restrict__ out)
{
    const int tid = threadIdx.x;
    const double w0 = 1.0 / (4.0 * 16.0 * 510.0 * 510.0);
    const double w1 = 1.0 / (4.0 * 16.0 * 254.0 * 254.0);
    const double w2 = 1.0 / (4.0 * 16.0 * 126.0 * 126.0);
    const double w3 = 1.0 / (4.0 * 16.0 * 62.0 * 62.0);
    double v = 0.0;
    for (int i = tid; i < NTOT; i += 256) {
        double w = (i < N0) ? w0 : (i < N0 + N1) ? w1 : (i < N0 + N1 + N2) ? w2 : w3;
        v += (double)P[i] * w;
    }
    for (int off = 32; off; off >>= 1) v += __shfl_down(v, off, 64);
    __shared__ double wsum[4];
    if ((tid & 63) == 0) wsum[tid >> 6] = v;
    __syncthreads();
    if (tid == 0) out[0] = (float)(wsum[0] + wsum[1] + wsum[2] + wsum[3]);
}

extern "C" void kernel_launch(void* const* d_in, const int* in_sizes, int n_in,
                              void* d_out, int out_size, void* d_ws, size_t ws_size,
                              hipStream_t stream) {
    const float* Ii = (const float*)d_in[0];
    const float* Ir = (const float*)d_in[1];
    float* out = (float*)d_out;

    char* ws = (char*)d_ws;
    float* P  = (float*)ws;                              // NTOT partials
    float* X1 = P + NTOT;                                // 16 x 256 x 256 gray s1
    float* Y1 = X1 + 16 * 65536;

    msgms_scale0<<<N0 / 4, 256, 0, stream>>>(Ii, Ir, X1, Y1, P);
    msgms_rest  <<<(N1 + N2 + N3) / 4, 256, 0, stream>>>(X1, Y1, P);
    msgms_final <<<1, 256, 0, stream>>>(P, out);
}